// Round 11
// baseline (377.623 us; speedup 1.0000x reference)
//
#include <hip/hip_runtime.h>

#define N_IN 128
#define HID 256
#define NB 16
#define BM 128
#define HS_STRIDE 264   // bf16 row stride for H tile (16B pad)

typedef __attribute__((ext_vector_type(8))) short s8v;    // 8 bf16 = 4 VGPRs
typedef __attribute__((ext_vector_type(4))) float f4v;    // 16x16x32 acc / f32x4
typedef __attribute__((ext_vector_type(16))) float f16v;  // 32x32x16 acc

__device__ __forceinline__ unsigned short f2bf(float f) {
  unsigned int u = __float_as_uint(f);
  u += 0x7fffu + ((u >> 16) & 1u);   // round-to-nearest-even
  return (unsigned short)(u >> 16);
}

__device__ __forceinline__ float tanh_fast(float x) {
  float e = __expf(2.0f * x);
  return 1.0f - 2.0f * __builtin_amdgcn_rcpf(e + 1.0f);
}

// ================= Round-11 prep: fragment repack for 32x32x16 phase C ========
// W1f (UNCHANGED, 16x16x32 frags for phase B):
//   idx = (((pass*4+kk)*8+ct)*64+lane)*8+j, val = W1[k*256+n],
//   n = pass*128+ct*16+(lane&15), k = kk*32+(lane>>4)*8+j
// W2f (NEW, 32x32x16 B-frags): frag (b, ks, CT), ks=K/16 step (0..15), CT=32-col
//   tile (0..3):  idx = (((b*16+ks)*4+CT)*64+lane)*8+j
//   val = W2[(ks*16+(lane>>5)*8+j)*2048 + (CT*32+(lane&31))*16 + b]
__global__ void __launch_bounds__(256)
prep4_kernel(const float* __restrict__ W1, const float* __restrict__ W2,
             unsigned short* __restrict__ W1f, unsigned short* __restrict__ W2f) {
  __shared__ unsigned short T[8192];   // 16 KB bf16 tile

  const int t = threadIdx.x;
  const int lane = t & 63;
  const int wv = t >> 6;
  const int l15 = lane & 15;
  const int l31 = lane & 31;
  const int l4 = (lane >> 4) & 3;
  const int hi = lane >> 5;
  const int bid = blockIdx.x;

  if (bid < 64) {
    // ---- W2 tile: ks = bid>>2 (k-rows ks*16..+16), CT = bid&3 (cols CT*512..+512) ----
    const int ks = bid >> 2, CT = bid & 3;
    const float* src = W2 + (long)(ks * 16) * (N_IN * NB) + CT * 512;
#pragma unroll
    for (int it = 0; it < 8; ++it) {
      int idx = it * 256 + t;          // 0..2047 f4-chunks
      int r = idx >> 7;                // 0..15
      int c4 = idx & 127;              // f4 within 512 cols
      f4v v = __builtin_nontemporal_load((const f4v*)(src + r * (N_IN * NB) + c4 * 4));
      unsigned short* d = &T[r * 512 + c4 * 4];
      d[0] = f2bf(v[0]); d[1] = f2bf(v[1]); d[2] = f2bf(v[2]); d[3] = f2bf(v[3]);
    }
    __syncthreads();
    // ---- emit 16 frags (b 0..15), wave wv does b = fi*4+wv ----
#pragma unroll
    for (int fi = 0; fi < 4; ++fi) {
      int b = fi * 4 + wv;
      s8v v;
#pragma unroll
      for (int j = 0; j < 8; ++j)
        v[j] = (short)T[(hi * 8 + j) * 512 + l31 * 16 + b];
      *(s8v*)(W2f + ((((b * 16 + ks) * 4 + CT) * 64 + lane) << 3)) = v;
    }
  } else if (bid < 68) {
    // ---- W1 tile (verbatim from validated prep3): kk = bid-64 ----
    const int kk = bid - 64;
    const float* src = W1 + (long)(kk * 32) * HID;
#pragma unroll
    for (int it = 0; it < 8; ++it) {
      int idx = it * 256 + t;
      int r = idx >> 6;                // 0..31
      int c4 = idx & 63;
      f4v v = __builtin_nontemporal_load((const f4v*)(src + r * HID + c4 * 4));
      unsigned short* d = &T[r * 256 + c4 * 4];
      d[0] = f2bf(v[0]); d[1] = f2bf(v[1]); d[2] = f2bf(v[2]); d[3] = f2bf(v[3]);
    }
    __syncthreads();
#pragma unroll
    for (int fi = 0; fi < 4; ++fi) {
      int f = fi * 4 + wv;
      int pass = f >> 3, ct = f & 7;
      int col = pass * 128 + ct * 16 + l15;
      s8v v;
#pragma unroll
      for (int j = 0; j < 8; ++j)
        v[j] = (short)T[(l4 * 8 + j) * 256 + col];
      *(s8v*)(W1f + ((((pass * 4 + kk) * 8 + ct) * 64 + lane) << 3)) = v;
    }
  }
}

// ================= Fused kernel: phase B 16x16x32 (proven), phase C 32x32x16 ====
__global__ void __launch_bounds__(256, 2)
pilayer_kernel(const float* __restrict__ prop,
               const int* __restrict__ idx_i,
               const int* __restrict__ idx_j,
               const float* __restrict__ basis,
               const unsigned short* __restrict__ W1f,
               const unsigned short* __restrict__ W2f,
               float* __restrict__ out, int P) {
  __shared__ unsigned short Hs[BM * HS_STRIDE];   // 67,584 B
  __shared__ float basisT[NB * BM];               //  8,192 B (TRANSPOSED: [b][row])

  const int t = threadIdx.x;
  const int lane = t & 63;
  const int wv = t >> 6;
  const int l15 = lane & 15;
  const int l31 = lane & 31;
  const int l4 = (lane >> 4) & 3;
  const int hi = lane >> 5;
  const int tile0 = blockIdx.x * BM;
  const int row0 = wv * 32;

  // ---- edge indices at kernel top ----
  int pidx[2], qidx[2];
#pragma unroll
  for (int rt = 0; rt < 2; ++rt) {
    int p = tile0 + row0 + rt * 16 + l15; if (p >= P) p = P - 1;
    pidx[rt] = idx_i[p];
    qidx[rt] = idx_j[p];
  }

  // ---- stage basis TRANSPOSED: basisT[b*128 + r] = basis[tile0+r][b] ----
  {
    int r = t >> 1;
    int c0 = (t & 1) * 8;
    int p = tile0 + r; if (p >= P) p = P - 1;
    const f4v* bp = (const f4v*)(basis + (long)p * NB + c0);
    f4v b0 = __builtin_nontemporal_load(bp);
    f4v b1 = __builtin_nontemporal_load(bp + 1);
#pragma unroll
    for (int u = 0; u < 4; ++u) {
      basisT[(c0 + u) * BM + r] = b0[u];
      basisT[(c0 + 4 + u) * BM + r] = b1[u];
    }
  }

  // ---- Phase B (verbatim proven): wave wv computes H rows [32wv,32wv+32) ----
  {
    s8v afr[4][2];
#pragma unroll
    for (int kk = 0; kk < 4; ++kk) {
      int k0 = kk * 32 + l4 * 8;
#pragma unroll
      for (int rt = 0; rt < 2; ++rt) {
        const float4* ai = (const float4*)(prop + (long)pidx[rt] * N_IN + k0);
        const float4* aj = (const float4*)(prop + (long)qidx[rt] * N_IN + k0);
        float4 x0 = ai[0], x1 = ai[1];
        float4 y0 = aj[0], y1 = aj[1];
        s8v a;
        a[0] = (short)f2bf(x0.x + y0.x); a[1] = (short)f2bf(x0.y + y0.y);
        a[2] = (short)f2bf(x0.z + y0.z); a[3] = (short)f2bf(x0.w + y0.w);
        a[4] = (short)f2bf(x1.x + y1.x); a[5] = (short)f2bf(x1.y + y1.y);
        a[6] = (short)f2bf(x1.z + y1.z); a[7] = (short)f2bf(x1.w + y1.w);
        afr[kk][rt] = a;
      }
    }
#pragma unroll
    for (int pass = 0; pass < 2; ++pass) {
      f4v acc[2][8];
#pragma unroll
      for (int rt = 0; rt < 2; ++rt)
#pragma unroll
        for (int ct = 0; ct < 8; ++ct) acc[rt][ct] = (f4v){0.f, 0.f, 0.f, 0.f};
#pragma unroll
      for (int kk = 0; kk < 4; ++kk) {
#pragma unroll
        for (int ct = 0; ct < 8; ++ct) {
          s8v bfr = *(const s8v*)(W1f + ((((pass * 4 + kk) * 8 + ct) * 64 + lane) << 3));
#pragma unroll
          for (int rt = 0; rt < 2; ++rt)
            acc[rt][ct] = __builtin_amdgcn_mfma_f32_16x16x32_bf16(afr[kk][rt], bfr, acc[rt][ct], 0, 0, 0);
        }
      }
#pragma unroll
      for (int rt = 0; rt < 2; ++rt)
#pragma unroll
        for (int ct = 0; ct < 8; ++ct)
#pragma unroll
          for (int r = 0; r < 4; ++r) {
            int lrow = row0 + rt * 16 + l4 * 4 + r;
            int col = pass * 128 + ct * 16 + l15;
            Hs[lrow * HS_STRIDE + col] = f2bf(tanh_fast(acc[rt][ct][r]));
          }
    }
  }

  __syncthreads();   // H + basisT visible

  // ---- Phase C: 32x32x16 MFMA. Wave (rg,cg): rows rg*64..+64, c-cols cg*64..+64.
  // A layout: row=lane&31, k=(lane>>5)*8+j. B: col=lane&31, same k.
  // C/D: col=lane&31, row=(reg&3)+8*(reg>>2)+4*(lane>>5)  [guide m74/m101]. ----
  const int rg = wv >> 1, cg = wv & 1;
  const int rbase = rg * 64;

  f16v o[2][2];   // [rt2][ct]: rows rbase+rt2*32.., c-cols cg*64+ct*32..
#pragma unroll
  for (int rt2 = 0; rt2 < 2; ++rt2)
#pragma unroll
    for (int ct = 0; ct < 2; ++ct)
#pragma unroll
      for (int e = 0; e < 16; ++e) o[rt2][ct][e] = 0.f;

  s8v bf[2][4];   // double buffer: [kc-parity][kl]

#pragma unroll 1
  for (int khalf = 0; khalf < 2; ++khalf) {
    // A-cache: [rt2][ksl] 16 frags (64 VGPR)
    s8v areg[2][8];
#pragma unroll
    for (int rt2 = 0; rt2 < 2; ++rt2)
#pragma unroll
      for (int ksl = 0; ksl < 8; ++ksl)
        areg[rt2][ksl] = *(const s8v*)&Hs[(rbase + rt2 * 32 + l31) * HS_STRIDE +
                                          khalf * 128 + ksl * 16 + hi * 8];

    // prologue: preload (b=0, ct=0, kc=0)
#pragma unroll
    for (int kl = 0; kl < 4; ++kl) {
      int ks = khalf * 8 + kl;
      bf[0][kl] = *(const s8v*)(W2f + ((((0 * 16 + ks) * 4 + cg * 2 + 0) * 64 + lane) << 3));
    }

#pragma unroll 1
    for (int b = 0; b < 16; ++b) {
      // bs: broadcast b128 reads (2 addrs/wave), [rt2][q4] covers reg&3
      f4v bsv[2][4];
#pragma unroll
      for (int rt2 = 0; rt2 < 2; ++rt2)
#pragma unroll
        for (int q4 = 0; q4 < 4; ++q4)
          bsv[rt2][q4] = *(const f4v*)&basisT[b * BM + rbase + rt2 * 32 + q4 * 8 + hi * 4];

#pragma unroll
      for (int ct = 0; ct < 2; ++ct) {
        f16v g[2];
#pragma unroll
        for (int rt2 = 0; rt2 < 2; ++rt2)
#pragma unroll
          for (int e = 0; e < 16; ++e) g[rt2][e] = 0.f;

#pragma unroll
        for (int kc = 0; kc < 2; ++kc) {
          // prefetch next kc-step into the other buffer (distance 1: 4 loads
          // in flight under 8 MFMA = ~260 cyc > L2 latency; W2f is L2-warm)
          {
            int nb = b, nct = ct, nkc = kc ^ 1;
            if (kc == 1) { nct = ct ^ 1; if (ct == 1) { nb = b + 1; if (nb > 15) nb = 15; } nkc = 0; }
#pragma unroll
            for (int kl = 0; kl < 4; ++kl) {
              int ks = khalf * 8 + nkc * 4 + kl;
              bf[kc ^ 1][kl] = *(const s8v*)(W2f +
                  ((((nb * 16 + ks) * 4 + cg * 2 + nct) * 64 + lane) << 3));
            }
          }
          __builtin_amdgcn_s_setprio(1);
#pragma unroll
          for (int kl = 0; kl < 4; ++kl)
#pragma unroll
            for (int rt2 = 0; rt2 < 2; ++rt2)
              g[rt2] = __builtin_amdgcn_mfma_f32_32x32x16_bf16(areg[rt2][kc * 4 + kl],
                                                               bf[kc][kl], g[rt2], 0, 0, 0);
          __builtin_amdgcn_s_setprio(0);
        }
        // o += g * bs  (row(reg) = (reg&3)+8*(reg>>2)+4*hi; bs row-indexed)
#pragma unroll
        for (int rt2 = 0; rt2 < 2; ++rt2)
#pragma unroll
          for (int reg = 0; reg < 16; ++reg)
            o[rt2][ct][reg] += g[rt2][reg] * bsv[rt2][reg >> 2][reg & 3];
      }
    }
  }

  // ---- epilogue: p = tile0+rbase+rt2*32+row(reg), ccol = cg*64+ct*32+l31 ----
#pragma unroll
  for (int rt2 = 0; rt2 < 2; ++rt2)
#pragma unroll
    for (int reg = 0; reg < 16; ++reg) {
      int p = tile0 + rbase + rt2 * 32 + (reg & 3) + 8 * (reg >> 2) + 4 * hi;
      if (p < P) {
        float* op = out + (long)p * N_IN + cg * 64 + l31;
#pragma unroll
        for (int ct = 0; ct < 2; ++ct)
          __builtin_nontemporal_store(o[rt2][ct][reg], op + ct * 32);
      }
    }
}

extern "C" void kernel_launch(void* const* d_in, const int* in_sizes, int n_in,
                              void* d_out, int out_size, void* d_ws, size_t ws_size,
                              hipStream_t stream) {
  const float* prop  = (const float*)d_in[0];
  const int* idx_i   = (const int*)d_in[1];
  const int* idx_j   = (const int*)d_in[2];
  const float* basis = (const float*)d_in[3];
  const float* W1    = (const float*)d_in[4];
  const float* W2    = (const float*)d_in[5];
  float* out = (float*)d_out;
  int P = in_sizes[1];

  unsigned short* W1f = (unsigned short*)d_ws;                 // 32768 bf16
  unsigned short* W2f = W1f + N_IN * HID;                      // 524288 bf16

  prep4_kernel<<<68, 256, 0, stream>>>(W1, W2, W1f, W2f);

  int ntiles = (P + BM - 1) / BM;
  pilayer_kernel<<<ntiles, 256, 0, stream>>>(prop, idx_i, idx_j, basis, W1f, W2f, out, P);
}

// Round 12
// 327.402 us; speedup vs baseline: 1.1534x; 1.1534x over previous
//
#include <hip/hip_runtime.h>

#define N_IN 128
#define HID 256
#define NB 16
#define BM 128
#define HS_STRIDE 264   // bf16 row stride for H tile (16B pad -> 2-way banks only, free)

typedef __attribute__((ext_vector_type(8))) short s8v;   // 8 bf16 = 4 VGPRs
typedef __attribute__((ext_vector_type(4))) float f4v;   // MFMA 16x16x32 accumulator

__device__ __forceinline__ unsigned short f2bf(float f) {
  unsigned int u = __float_as_uint(f);
  u += 0x7fffu + ((u >> 16) & 1u);   // round-to-nearest-even
  return (unsigned short)(u >> 16);
}

__device__ __forceinline__ float tanh_fast(float x) {
  float e = __expf(2.0f * x);
  return 1.0f - 2.0f * __builtin_amdgcn_rcpf(e + 1.0f);
}

// ================= prep3 (round-10 validated, verbatim) =================
// W1f idx = (((pass*4+kk)*8+ct)*64+lane)*8+j, val = W1[k*256 + n],
//     n = pass*128+ct*16+(lane&15), k = kk*32+(lane>>4)*8+j
// W2f idx = (((b*8+kk)*8+ct)*64+lane)*8+j,   val = W2[k*2048 + n*16+b],
//     n = ct*16+(lane&15),          k = kk*32+(lane>>4)*8+j
__global__ void __launch_bounds__(256)
prep3_kernel(const float* __restrict__ W1, const float* __restrict__ W2,
             unsigned short* __restrict__ W1f, unsigned short* __restrict__ W2f) {
  __shared__ unsigned short T[32 * 256];   // 16 KB bf16 tile

  const int t = threadIdx.x;
  const int lane = t & 63;
  const int wv = t >> 6;
  const int l15 = lane & 15;
  const int l4 = lane >> 4;
  const int bid = blockIdx.x;

  const bool isW2 = bid < 64;
  const int kk = isW2 ? (bid >> 3) : (bid - 64);
  const int ctile = isW2 ? (bid & 7) : 0;
  const float* src = isW2 ? (W2 + (long)(kk * 32) * (N_IN * NB) + ctile * 256)
                          : (W1 + (long)(kk * 32) * HID);
  const int srcStride = isW2 ? (N_IN * NB) : HID;

#pragma unroll
  for (int it = 0; it < 8; ++it) {
    int idx = it * 256 + t;
    int r = idx >> 6;
    int c4 = idx & 63;
    f4v v = __builtin_nontemporal_load((const f4v*)(src + r * srcStride + c4 * 4));
    unsigned short* d = &T[r * 256 + c4 * 4];
    d[0] = f2bf(v[0]); d[1] = f2bf(v[1]); d[2] = f2bf(v[2]); d[3] = f2bf(v[3]);
  }
  __syncthreads();

#pragma unroll
  for (int fi = 0; fi < 4; ++fi) {
    int f = fi * 4 + wv;
    s8v v;
    if (isW2) {
      int b = f;
      int colb = l15 * 16 + b;
#pragma unroll
      for (int j = 0; j < 8; ++j)
        v[j] = (short)T[(l4 * 8 + j) * 256 + colb];
      *(s8v*)(W2f + ((((b * 8 + kk) * 8 + ctile) * 64 + lane) << 3)) = v;
    } else {
      int pass = f >> 3, ct = f & 7;
      int col = pass * 128 + ct * 16 + l15;
#pragma unroll
      for (int j = 0; j < 8; ++j)
        v[j] = (short)T[(l4 * 8 + j) * 256 + col];
      *(s8v*)(W1f + ((((pass * 4 + kk) * 8 + ct) * 64 + lane) << 3)) = v;
    }
  }
}

// ================= Round-12: round-10 structure + 2 isolated micro-opts =========
// (1) basisT transposed staging (validated r11: correct + conflicts 900k->100k),
//     bs via f4v broadcast reads. (2) packed o-update via elementwise_fma
//     (v_pk_fma_f32, halves o-update VALU issues; register-neutral).
__global__ void __launch_bounds__(256, 2)
pilayer_kernel(const float* __restrict__ prop,
               const int* __restrict__ idx_i,
               const int* __restrict__ idx_j,
               const float* __restrict__ basis,
               const unsigned short* __restrict__ W1f,
               const unsigned short* __restrict__ W2f,
               float* __restrict__ out, int P) {
  __shared__ unsigned short Hs[BM * HS_STRIDE];   // 67,584 B (live through phase C)
  __shared__ float basisT[NB * BM];               //  8,192 B (TRANSPOSED [b][row]) -> 75.8 KB

  const int t = threadIdx.x;
  const int lane = t & 63;
  const int wv = t >> 6;
  const int l15 = lane & 15;
  const int l4 = lane >> 4;
  const int tile0 = blockIdx.x * BM;
  const int row0 = wv * 32;

  // ---- edge indices at kernel top: head of the idx->prop pointer-chase ----
  int pidx[2], qidx[2];
#pragma unroll
  for (int rt = 0; rt < 2; ++rt) {
    int p = tile0 + row0 + rt * 16 + l15; if (p >= P) p = P - 1;
    pidx[rt] = idx_i[p];
    qidx[rt] = idx_j[p];
  }

  // ---- stage basis TRANSPOSED: basisT[b*128 + r] = basis[tile0+r][b] (r11-validated) ----
  {
    int r = t >> 1;
    int c0 = (t & 1) * 8;
    int p = tile0 + r; if (p >= P) p = P - 1;
    const f4v* bp = (const f4v*)(basis + (long)p * NB + c0);
    f4v b0 = __builtin_nontemporal_load(bp);
    f4v b1 = __builtin_nontemporal_load(bp + 1);
#pragma unroll
    for (int u = 0; u < 4; ++u) {
      basisT[(c0 + u) * BM + r] = b0[u];
      basisT[(c0 + 4 + u) * BM + r] = b1[u];
    }
  }

  // ---- Phase B (verbatim proven): wave wv computes H rows [32wv,32wv+32) ----
  {
    s8v afr[4][2];   // [kk][rt], 32 VGPR; gathers issued once, reused by both passes
#pragma unroll
    for (int kk = 0; kk < 4; ++kk) {
      int k0 = kk * 32 + l4 * 8;
#pragma unroll
      for (int rt = 0; rt < 2; ++rt) {
        const float4* ai = (const float4*)(prop + (long)pidx[rt] * N_IN + k0);
        const float4* aj = (const float4*)(prop + (long)qidx[rt] * N_IN + k0);
        float4 x0 = ai[0], x1 = ai[1];
        float4 y0 = aj[0], y1 = aj[1];
        s8v a;
        a[0] = (short)f2bf(x0.x + y0.x); a[1] = (short)f2bf(x0.y + y0.y);
        a[2] = (short)f2bf(x0.z + y0.z); a[3] = (short)f2bf(x0.w + y0.w);
        a[4] = (short)f2bf(x1.x + y1.x); a[5] = (short)f2bf(x1.y + y1.y);
        a[6] = (short)f2bf(x1.z + y1.z); a[7] = (short)f2bf(x1.w + y1.w);
        afr[kk][rt] = a;
      }
    }
#pragma unroll
    for (int pass = 0; pass < 2; ++pass) {
      f4v acc[2][8];
#pragma unroll
      for (int rt = 0; rt < 2; ++rt)
#pragma unroll
        for (int ct = 0; ct < 8; ++ct) acc[rt][ct] = (f4v){0.f, 0.f, 0.f, 0.f};
#pragma unroll
      for (int kk = 0; kk < 4; ++kk) {
#pragma unroll
        for (int ct = 0; ct < 8; ++ct) {
          s8v bfr = *(const s8v*)(W1f + ((((pass * 4 + kk) * 8 + ct) * 64 + lane) << 3));
#pragma unroll
          for (int rt = 0; rt < 2; ++rt)
            acc[rt][ct] = __builtin_amdgcn_mfma_f32_16x16x32_bf16(afr[kk][rt], bfr, acc[rt][ct], 0, 0, 0);
        }
      }
#pragma unroll
      for (int rt = 0; rt < 2; ++rt)
#pragma unroll
        for (int ct = 0; ct < 8; ++ct)
#pragma unroll
          for (int r = 0; r < 4; ++r) {
            int lrow = row0 + rt * 16 + l4 * 4 + r;
            int col = pass * 128 + ct * 16 + l15;
            Hs[lrow * HS_STRIDE + col] = f2bf(tanh_fast(acc[rt][ct][r]));
          }
    }
  }

  __syncthreads();   // H + basisT visible to all waves

  // ---- Phase C (round-10 structure): 2x2 wave partition; wave (rg,cg) owns
  // rows rg*64..+64, cols cg*64..+64. A in registers per K-half; B ring depth 3. ----
  const int rg = wv >> 1, cg = wv & 1;
  const int rbase = rg * 64;

  f4v o[4][4];   // [rt][q] -> rows rbase+rt*16.., cols (cg*4+q)*16..
#pragma unroll
  for (int rt = 0; rt < 4; ++rt)
#pragma unroll
    for (int q = 0; q < 4; ++q) o[rt][q] = (f4v){0.f, 0.f, 0.f, 0.f};

#pragma unroll 1
  for (int khalf = 0; khalf < 2; ++khalf) {
    // A-cache: 16 fragments (64 VGPR), reused across all 16 b and 4 q
    s8v areg[4][4];   // [rt][kloc]
#pragma unroll
    for (int rt = 0; rt < 4; ++rt)
#pragma unroll
      for (int kloc = 0; kloc < 4; ++kloc)
        areg[rt][kloc] = *(const s8v*)&Hs[(rbase + rt * 16 + l15) * HS_STRIDE +
                                          (khalf * 4 + kloc) * 32 + l4 * 8];

    s8v bf[4][4];   // register ring of B fragments [slot][kloc], slot = it & 3
    // preload iterations 0,1,2  (b=0, q=0..2)
#pragma unroll
    for (int q0 = 0; q0 < 3; ++q0)
#pragma unroll
      for (int kloc = 0; kloc < 4; ++kloc)
        bf[q0][kloc] = *(const s8v*)(W2f +
            ((((khalf * 4 + kloc) * 8) + cg * 4 + q0) << 9) + lane * 8);

#pragma unroll 1
    for (int b = 0; b < 16; ++b) {
      // bs: 4 f4v broadcast reads (rows rbase+rt*16+l4*4 .. +4), replaces 16 scalar
      f4v bsv[4];
#pragma unroll
      for (int rt = 0; rt < 4; ++rt)
        bsv[rt] = *(const f4v*)&basisT[b * BM + rbase + rt * 16 + l4 * 4];

#pragma unroll
      for (int q = 0; q < 4; ++q) {
        // prefetch iteration it+3 into slot (q+3)&3  (it = b*4+q)
        {
          int nb = b + ((q + 3) >> 2); if (nb > 15) nb = 15;   // tail: harmless re-read
          int nq = (q + 3) & 3;
#pragma unroll
          for (int kloc = 0; kloc < 4; ++kloc)
            bf[(q + 3) & 3][kloc] = *(const s8v*)(W2f +
                (((nb * 8 + khalf * 4 + kloc) * 8 + cg * 4 + nq) << 9) + lane * 8);
        }
        f4v g[4];
#pragma unroll
        for (int rt = 0; rt < 4; ++rt) g[rt] = (f4v){0.f, 0.f, 0.f, 0.f};
        __builtin_amdgcn_s_setprio(1);   // T5: barrier-free independent waves in b-loop
#pragma unroll
        for (int kloc = 0; kloc < 4; ++kloc)
#pragma unroll
          for (int rt = 0; rt < 4; ++rt)
            g[rt] = __builtin_amdgcn_mfma_f32_16x16x32_bf16(areg[rt][kloc], bf[q][kloc], g[rt], 0, 0, 0);
        __builtin_amdgcn_s_setprio(0);
        // packed o-update: v_pk_fma_f32 (f4v elementwise fma), register-neutral
#pragma unroll
        for (int rt = 0; rt < 4; ++rt)
          o[rt][q] = __builtin_elementwise_fma(g[rt], bsv[rt], o[rt][q]);
      }
    }
  }

  // ---- epilogue: out[p][c], c = (cg*4+q)*16 + l15. Non-temporal: out is
  // write-once/never-read -> keep it from evicting W2f out of L2. ----
#pragma unroll
  for (int rt = 0; rt < 4; ++rt)
#pragma unroll
    for (int r = 0; r < 4; ++r) {
      int p = tile0 + rbase + rt * 16 + l4 * 4 + r;
      if (p < P) {
        float* op = out + (long)p * N_IN + cg * 64 + l15;
#pragma unroll
        for (int q = 0; q < 4; ++q)
          __builtin_nontemporal_store(o[rt][q][r], op + q * 16);
      }
    }
}

extern "C" void kernel_launch(void* const* d_in, const int* in_sizes, int n_in,
                              void* d_out, int out_size, void* d_ws, size_t ws_size,
                              hipStream_t stream) {
  const float* prop  = (const float*)d_in[0];
  const int* idx_i   = (const int*)d_in[1];
  const int* idx_j   = (const int*)d_in[2];
  const float* basis = (const float*)d_in[3];
  const float* W1    = (const float*)d_in[4];
  const float* W2    = (const float*)d_in[5];
  float* out = (float*)d_out;
  int P = in_sizes[1];

  unsigned short* W1f = (unsigned short*)d_ws;                 // 32768 bf16
  unsigned short* W2f = W1f + N_IN * HID;                      // 524288 bf16

  prep3_kernel<<<68, 256, 0, stream>>>(W1, W2, W1f, W2f);

  int ntiles = (P + BM - 1) / BM;
  pilayer_kernel<<<ntiles, 256, 0, stream>>>(prop, idx_i, idx_j, basis, W1f, W2f, out, P);
}